// Round 16
// baseline (31.995 us; speedup 1.0000x reference)
//
#include <hip/hip_runtime.h>
#include <math.h>

#define H 8
#define B 64
#define D 512
#define EPS 1e-8f
#define INV_SQRT_D 0.04419417382415922f   // 1/sqrt(512)
#define LN2 0.6931471805599453f
#define EPS_LN2 6.931471805599453e-9f     // EPS * ln(2)
#define SCH_A 8388608.0f                  // 2^23
#define SCH_B 1064986823.0f               // (127 - 0.0436774)*2^23, rel err ~3%

__device__ __forceinline__ float fast_rcp(float x) { return __builtin_amdgcn_rcpf(x); }
__device__ __forceinline__ float fast_exp2(float x) { return __builtin_amdgcn_exp2f(x); }

// Approx 2^(r - tmax), c_row = SCH_B - tmax*2^23.
// (unsigned) cast -> v_cvt_u32_f32 saturates negatives to 0 (far terms -> +0.0).
__device__ __forceinline__ float sch_exp2(float r, float c_row) {
    const float u = fmaf(r, SCH_A, c_row);
    return __uint_as_float((unsigned)u);
}

// ---------------------------------------------------------------------------
// Single fused kernel (R15 structure). Block = (b, 64-row chunk);
// 1024 threads = (half, h, r). Micro-opts: v_min3-friendly pass-1,
// 8-chain / 8-elem-per-iter pass-2 for deeper ILP over rcp latency.
// ---------------------------------------------------------------------------
__global__ __launch_bounds__(1024, 2) void attn_all(
    const float* __restrict__ x,
    const float* __restrict__ Wq, const float* __restrict__ bq,
    const float* __restrict__ Wk, const float* __restrict__ bk,
    const float* __restrict__ Wv, const float* __restrict__ bv,
    float* __restrict__ out)
{
    const int blk = blockIdx.x;         // b*8 + chunk
    const int b = blk >> 3;
    const int chunk = blk & 7;
    const int t = threadIdx.x;          // 0..1023
    const int r6 = t & 63;              // row in chunk
    const int h = (t >> 6) & 7;         // head
    const int half = t >> 9;            // j-half
    const int i = chunk * 64 + r6;      // global row 0..511

    __shared__ __align__(16) float qs[H * D];   // 16 KB
    __shared__ __align__(16) float vs[H * D];   // 16 KB
    __shared__ float mT[H * 64], mL[H * 64], mA[H * 64];  // 6 KB

    // --- stage q,v for all heads: thread t owns flat elements 4t..4t+3 ---
    {
        const float4 wq = reinterpret_cast<const float4*>(Wq)[t];
        const float4 bqv = reinterpret_cast<const float4*>(bq)[t];
        const float4 wv = reinterpret_cast<const float4*>(Wv)[t];
        const float4 bvv = reinterpret_cast<const float4*>(bv)[t];
        const float4 xx = reinterpret_cast<const float4*>(x + b * D)[t & 127];
        float4 qq, vv;
        qq.x = fmaf(wq.x, xx.x, bqv.x);  vv.x = fmaf(wv.x, xx.x, bvv.x);
        qq.y = fmaf(wq.y, xx.y, bqv.y);  vv.y = fmaf(wv.y, xx.y, bvv.y);
        qq.z = fmaf(wq.z, xx.z, bqv.z);  vv.z = fmaf(wv.z, xx.z, bvv.z);
        qq.w = fmaf(wq.w, xx.w, bqv.w);  vv.w = fmaf(wv.w, xx.w, bvv.w);
        reinterpret_cast<float4*>(qs)[t] = qq;
        reinterpret_cast<float4*>(vs)[t] = vv;
    }
    const float xi = x[b * D + i];
    const float k = fmaf(Wk[h * D + i], xi, bk[h * D + i]);
    __syncthreads();

    const float4* q4 = reinterpret_cast<const float4*>(qs + h * D) + half * (D / 8);
    const float4* v4 = reinterpret_cast<const float4*>(vs + h * D) + half * (D / 8);

    // --- pass 1: dmin, min3-fused (min(m, min(|a|,|b|)) -> v_min3_f32) ---
    float m0 = INFINITY, m1 = INFINITY, m2 = INFINITY, m3 = INFINITY;
    for (int j = 0; j < D / 16; ++j) {
        const float4 qa = q4[2 * j];
        const float4 qb = q4[2 * j + 1];
        m0 = fminf(m0, fminf(fabsf(qa.x - k), fabsf(qa.y - k)));
        m1 = fminf(m1, fminf(fabsf(qa.z - k), fabsf(qa.w - k)));
        m2 = fminf(m2, fminf(fabsf(qb.x - k), fabsf(qb.y - k)));
        m3 = fminf(m3, fminf(fabsf(qb.z - k), fabsf(qb.w - k)));
    }
    const float dmin = fminf(fminf(m0, m1), fminf(m2, m3));
    const float tmax = fast_rcp(fmaf(dmin, LN2, EPS_LN2));
    const float c_row = SCH_B - tmax * SCH_A;

    // --- pass 2: 8 chains, 8 elements per iteration ---
    float l0 = 0.f, l1 = 0.f, l2 = 0.f, l3 = 0.f;
    float l4 = 0.f, l5 = 0.f, l6 = 0.f, l7 = 0.f;
    float a0 = 0.f, a1 = 0.f, a2 = 0.f, a3 = 0.f;
    float a4 = 0.f, a5 = 0.f, a6 = 0.f, a7 = 0.f;
    for (int j = 0; j < D / 16; ++j) {
        const float4 qa = q4[2 * j];
        const float4 qb = q4[2 * j + 1];
        const float r0 = fast_rcp(fmaf(fabsf(qa.x - k), LN2, EPS_LN2));
        const float r1 = fast_rcp(fmaf(fabsf(qa.y - k), LN2, EPS_LN2));
        const float r2 = fast_rcp(fmaf(fabsf(qa.z - k), LN2, EPS_LN2));
        const float r3 = fast_rcp(fmaf(fabsf(qa.w - k), LN2, EPS_LN2));
        const float r4 = fast_rcp(fmaf(fabsf(qb.x - k), LN2, EPS_LN2));
        const float r5 = fast_rcp(fmaf(fabsf(qb.y - k), LN2, EPS_LN2));
        const float r6c = fast_rcp(fmaf(fabsf(qb.z - k), LN2, EPS_LN2));
        const float r7 = fast_rcp(fmaf(fabsf(qb.w - k), LN2, EPS_LN2));
        const float4 va = v4[2 * j];
        const float4 vb = v4[2 * j + 1];
        const float e0 = sch_exp2(r0, c_row);
        const float e1 = sch_exp2(r1, c_row);
        const float e2 = sch_exp2(r2, c_row);
        const float e3 = sch_exp2(r3, c_row);
        const float e4 = sch_exp2(r4, c_row);
        const float e5 = sch_exp2(r5, c_row);
        const float e6 = sch_exp2(r6c, c_row);
        const float e7 = sch_exp2(r7, c_row);
        l0 += e0; a0 = fmaf(e0, va.x, a0);
        l1 += e1; a1 = fmaf(e1, va.y, a1);
        l2 += e2; a2 = fmaf(e2, va.z, a2);
        l3 += e3; a3 = fmaf(e3, va.w, a3);
        l4 += e4; a4 = fmaf(e4, vb.x, a4);
        l5 += e5; a5 = fmaf(e5, vb.y, a5);
        l6 += e6; a6 = fmaf(e6, vb.z, a6);
        l7 += e7; a7 = fmaf(e7, vb.w, a7);
    }
    const float l = ((l0 + l1) + (l2 + l3)) + ((l4 + l5) + (l6 + l7));
    const float a = ((a0 + a1) + (a2 + a3)) + ((a4 + a5) + (a6 + a7));

    // --- merge halves in LDS (exact exp2 rescale) ---
    if (half == 1) { mT[h * 64 + r6] = tmax; mL[h * 64 + r6] = l; mA[h * 64 + r6] = a; }
    __syncthreads();
    if (half == 0) {
        const float T1 = mT[h * 64 + r6], L1 = mL[h * 64 + r6], A1 = mA[h * 64 + r6];
        const float m  = fmaxf(tmax, T1);
        const float s0 = fast_exp2(tmax - m);
        const float s1 = fast_exp2(T1 - m);
        const float L  = fmaf(L1, s1, l * s0);
        const float A  = fmaf(A1, s1, a * s0);
        mT[h * 64 + r6] = A * fast_rcp(L) * INV_SQRT_D;   // reuse mT for att
    }
    __syncthreads();

    // --- h-reduce + residual + store (threads 0..63) ---
    if (t < 64) {
        float s = xi;                       // t<64 => h==0, r6==t => xi = x[b,i]
        #pragma unroll
        for (int hh = 0; hh < H; ++hh) s += mT[hh * 64 + t];
        out[b * D + chunk * 64 + t] = s;
    }
}

extern "C" void kernel_launch(void* const* d_in, const int* in_sizes, int n_in,
                              void* d_out, int out_size, void* d_ws, size_t ws_size,
                              hipStream_t stream) {
    const float* x  = (const float*)d_in[0];
    const float* Wq = (const float*)d_in[1];
    const float* bq = (const float*)d_in[2];
    const float* Wk = (const float*)d_in[3];
    const float* bk = (const float*)d_in[4];
    const float* Wv = (const float*)d_in[5];
    const float* bv = (const float*)d_in[6];
    float* out = (float*)d_out;

    attn_all<<<B * (D / 64), 1024, 0, stream>>>(x, Wq, bq, Wk, bk, Wv, bv, out);
}